// Round 1
// baseline (3907.505 us; speedup 1.0000x reference)
//
#include <hip/hip_runtime.h>
#include <cstddef>
#include <cstdint>

#define N_USER 100000
#define N_ITEM 100000
#define N_EDGE 1000000
#define IN_DIM 256
#define HID 128
#define OUT_DIM 16
#define LEAKY_SLOPE 0.01f

// ---------------------------------------------------------------------------
// C[M,128] = A[M,K] @ W[K,128] + bias   (K multiple of 64; fp32 vector ALU)
// 64x128 block tile, K-chunk 64. A staged transposed (As[k][row]) so both
// operand fragments are ds_read_b128. 4 rows x 8 cols per thread.
// ---------------------------------------------------------------------------
template<int K>
__global__ __launch_bounds__(256)
void gemm_bias_128(const float* __restrict__ A, const float* __restrict__ W,
                   const float* __restrict__ bias, float* __restrict__ C, int M) {
  __shared__ float As[64][68];    // [kk][row], +4 pad keeps 16B align, breaks stride
  __shared__ float Ws[64][132];   // [kk][col], +4 pad
  const int t  = threadIdx.x;
  const int row0 = blockIdx.x * 64;
  const int tx = t & 15;          // col group: cols {4tx..4tx+3, 64+4tx..}
  const int ty = t >> 4;          // row group: rows 4ty..4ty+3

  float acc[4][8];
#pragma unroll
  for (int i = 0; i < 4; ++i)
#pragma unroll
    for (int j = 0; j < 8; ++j) acc[i][j] = 0.f;

  const int la_k = t & 15;        // float4 index along K
  const int la_r = t >> 4;        // row 0..15 (then +16p)
  const int lw_c = t & 31;        // float4 index along N
  const int lw_k = t >> 5;        // 0..7 (then +8q)

  for (int k0 = 0; k0 < K; k0 += 64) {
    __syncthreads();
    // A tile -> LDS (transposed)
#pragma unroll
    for (int p = 0; p < 4; ++p) {
      int r = row0 + la_r + 16 * p;
      r = r < M ? r : M - 1;               // clamp; stores are guarded later
      const float4 v = *(const float4*)&A[(size_t)r * K + k0 + la_k * 4];
      As[la_k * 4 + 0][la_r + 16 * p] = v.x;
      As[la_k * 4 + 1][la_r + 16 * p] = v.y;
      As[la_k * 4 + 2][la_r + 16 * p] = v.z;
      As[la_k * 4 + 3][la_r + 16 * p] = v.w;
    }
    // W tile -> LDS
#pragma unroll
    for (int q = 0; q < 8; ++q) {
      const int kk = lw_k + 8 * q;
      *(float4*)&Ws[kk][lw_c * 4] =
          *(const float4*)&W[(size_t)(k0 + kk) * HID + lw_c * 4];
    }
    __syncthreads();
#pragma unroll 4
    for (int kk = 0; kk < 64; ++kk) {
      const float4 a  = *(const float4*)&As[kk][ty * 4];
      const float4 w0 = *(const float4*)&Ws[kk][tx * 4];
      const float4 w1 = *(const float4*)&Ws[kk][64 + tx * 4];
      const float av[4] = {a.x, a.y, a.z, a.w};
      const float wv[8] = {w0.x, w0.y, w0.z, w0.w, w1.x, w1.y, w1.z, w1.w};
#pragma unroll
      for (int i = 0; i < 4; ++i)
#pragma unroll
        for (int j = 0; j < 8; ++j) acc[i][j] += av[i] * wv[j];
    }
  }

  const float4 b0 = *(const float4*)&bias[tx * 4];
  const float4 b1 = *(const float4*)&bias[64 + tx * 4];
#pragma unroll
  for (int i = 0; i < 4; ++i) {
    const int r = row0 + ty * 4 + i;
    if (r < M) {
      float4 o0 = {acc[i][0] + b0.x, acc[i][1] + b0.y,
                   acc[i][2] + b0.z, acc[i][3] + b0.w};
      float4 o1 = {acc[i][4] + b1.x, acc[i][5] + b1.y,
                   acc[i][6] + b1.z, acc[i][7] + b1.w};
      *(float4*)&C[(size_t)r * HID + tx * 4] = o0;
      *(float4*)&C[(size_t)r * HID + 64 + tx * 4] = o1;
    }
  }
}

// ---------------------------------------------------------------------------
// in-degree counts
// ---------------------------------------------------------------------------
__global__ __launch_bounds__(256)
void count_deg(const int* __restrict__ dst, int* __restrict__ cnt, int n) {
  const int i = blockIdx.x * 256 + threadIdx.x;
  if (i < n) atomicAdd(&cnt[dst[i]], 1);
}

// ---------------------------------------------------------------------------
// edge scatter-add: acc[dst[e]] += wh[src[e]]   (32 lanes per edge, float4)
// ---------------------------------------------------------------------------
__global__ __launch_bounds__(256)
void scatter_add(const float* __restrict__ wh, const int* __restrict__ src,
                 const int* __restrict__ dst, float* __restrict__ acc, int nedge) {
  const int e = blockIdx.x * 8 + (threadIdx.x >> 5);
  if (e >= nedge) return;
  const int c = threadIdx.x & 31;
  const int s = src[e];
  const int d = dst[e];
  const float4 v = ((const float4*)(wh + (size_t)s * HID))[c];
  float* p = acc + (size_t)d * HID + (size_t)c * 4;
  atomicAdd(p + 0, v.x);
  atomicAdd(p + 1, v.y);
  atomicAdd(p + 2, v.z);
  atomicAdd(p + 3, v.w);
}

// ---------------------------------------------------------------------------
// in-place mean (acc /= max(cnt,1)) + optional leaky-relu
// ---------------------------------------------------------------------------
template<bool DO_LEAKY>
__global__ __launch_bounds__(256)
void finalize_mean(float* __restrict__ acc, const int* __restrict__ cnt, int nrows) {
  const int t = blockIdx.x * 256 + threadIdx.x;
  const int row = t >> 5;
  if (row >= nrows) return;
  const int c = t & 31;
  const int cn = cnt[row];
  const float inv = 1.0f / (float)(cn > 1 ? cn : 1);
  float4* p = (float4*)(acc + (size_t)row * HID) + c;
  float4 v = *p;
  v.x *= inv; v.y *= inv; v.z *= inv; v.w *= inv;
  if (DO_LEAKY) {
    v.x = v.x > 0.f ? v.x : LEAKY_SLOPE * v.x;
    v.y = v.y > 0.f ? v.y : LEAKY_SLOPE * v.y;
    v.z = v.z > 0.f ? v.z : LEAKY_SLOPE * v.z;
    v.w = v.w > 0.f ? v.w : LEAKY_SLOPE * v.w;
  }
  *p = v;
}

// ---------------------------------------------------------------------------
// out[M,16] = H[M,128] @ W[128,16] + bias ; 16 rows x 16 cols per block
// ---------------------------------------------------------------------------
__global__ __launch_bounds__(256)
void gemm_out16(const float* __restrict__ H, const float* __restrict__ W,
                const float* __restrict__ bias, float* __restrict__ out, int M) {
  __shared__ float Ws[HID * OUT_DIM];  // 2048 floats
  __shared__ float Hs[16 * HID];       // 2048 floats
  const int t = threadIdx.x;
  const int row0 = blockIdx.x * 16;
  {
    const float4* s0 = (const float4*)W;
    float4* dp = (float4*)Ws;
    dp[t]       = s0[t];
    dp[t + 256] = s0[t + 256];
    const float4* s1 = (const float4*)(H + (size_t)row0 * HID);
    float4* hp = (float4*)Hs;
    hp[t]       = s1[t];
    hp[t + 256] = s1[t + 256];
  }
  __syncthreads();
  const int r = t >> 4, c = t & 15;
  float s = bias[c];
  const float* h = &Hs[r * HID];
#pragma unroll 8
  for (int k = 0; k < HID; ++k) s += h[k] * Ws[k * OUT_DIM + c];
  out[(size_t)(row0 + r) * OUT_DIM + c] = s;
}

// ---------------------------------------------------------------------------
extern "C" void kernel_launch(void* const* d_in, const int* in_sizes, int n_in,
                              void* d_out, int out_size, void* d_ws, size_t ws_size,
                              hipStream_t stream) {
  const float* feat_user  = (const float*)d_in[0];
  // d_in[1] feat_item : dead code (never reaches the output)
  const int*   src_clicks = (const int*)d_in[2];
  const int*   dst_clicks = (const int*)d_in[3];
  const int*   src_cb     = (const int*)d_in[4];
  const int*   dst_cb     = (const int*)d_in[5];
  const float* Win_user   = (const float*)d_in[6];
  const float* bin_user   = (const float*)d_in[7];
  // d_in[8..9] Win_item/bin_item : dead
  const float* W0_clicks  = (const float*)d_in[10];
  const float* b0_clicks  = (const float*)d_in[11];
  // d_in[12..13] W0_cb/b0_cb : dead ; d_in[14..15] W1_clicks/b1_clicks : dead
  const float* W1_cb      = (const float*)d_in[16];
  const float* b1_cb      = (const float*)d_in[17];
  const float* Wout       = (const float*)d_in[18];
  const float* bout       = (const float*)d_in[19];
  float* out = (float*)d_out;

  const size_t SZ = (size_t)N_USER * HID * sizeof(float);  // 51.2 MB (N_USER==N_ITEM)
  char* ws = (char*)d_ws;
  float* buf0 = (float*)ws;            // x_u -> h_i0 -> h_u1
  float* buf1 = (float*)(ws + SZ);     // wh_u0 -> wh_i1
  int* cnt_item = (int*)(ws + 2 * SZ);
  int* cnt_user = cnt_item + N_ITEM;

  const int G64 = (N_USER + 63) / 64;        // 1563
  const int GE  = N_EDGE / 8;                // 125000
  const int GF  = (N_USER * 32) / 256;       // 12500

  // degrees (reused facts about the two edge sets)
  hipMemsetAsync(cnt_item, 0, (size_t)(N_ITEM + N_USER) * sizeof(int), stream);
  count_deg<<<(N_EDGE + 255) / 256, 256, 0, stream>>>(dst_clicks, cnt_item, N_EDGE);
  count_deg<<<(N_EDGE + 255) / 256, 256, 0, stream>>>(dst_cb, cnt_user, N_EDGE);

  // 1) x_u = feat_user @ Win_user + bin_user        -> buf0
  gemm_bias_128<IN_DIM><<<G64, 256, 0, stream>>>(feat_user, Win_user, bin_user, buf0, N_USER);
  // 2) wh_u0 = x_u @ W0_clicks + b0_clicks          -> buf1
  gemm_bias_128<HID><<<G64, 256, 0, stream>>>(buf0, W0_clicks, b0_clicks, buf1, N_USER);
  // 3) h_i0 = leaky(seg_mean(wh_u0[src_clicks], dst_clicks)) -> buf0 (in place over acc)
  hipMemsetAsync(buf0, 0, SZ, stream);
  scatter_add<<<GE, 256, 0, stream>>>(buf1, src_clicks, dst_clicks, buf0, N_EDGE);
  finalize_mean<true><<<GF, 256, 0, stream>>>(buf0, cnt_item, N_ITEM);
  // 4) wh_i1 = h_i0 @ W1_cb + b1_cb                 -> buf1
  gemm_bias_128<HID><<<G64, 256, 0, stream>>>(buf0, W1_cb, b1_cb, buf1, N_ITEM);
  // 5) h_u1 = seg_mean(wh_i1[src_cb], dst_cb)       -> buf0
  hipMemsetAsync(buf0, 0, SZ, stream);
  scatter_add<<<GE, 256, 0, stream>>>(buf1, src_cb, dst_cb, buf0, N_EDGE);
  finalize_mean<false><<<GF, 256, 0, stream>>>(buf0, cnt_user, N_USER);
  // 6) out = h_u1 @ Wout + bout
  gemm_out16<<<N_USER / 16, 256, 0, stream>>>(buf0, Wout, bout, out, N_USER);
}

// Round 2
// 1103.533 us; speedup vs baseline: 3.5409x; 3.5409x over previous
//
#include <hip/hip_runtime.h>
#include <cstddef>
#include <cstdint>

#define N_USER 100000
#define N_ITEM 100000
#define N_EDGE 1000000
#define IN_DIM 256
#define HID 128
#define OUT_DIM 16
#define LEAKY_SLOPE 0.01f

// ---------------------------------------------------------------------------
// C[M,128] = A[M,K] @ W[K,128] + bias   (K multiple of 64; fp32 vector ALU)
// ---------------------------------------------------------------------------
template<int K>
__global__ __launch_bounds__(256)
void gemm_bias_128(const float* __restrict__ A, const float* __restrict__ W,
                   const float* __restrict__ bias, float* __restrict__ C, int M) {
  __shared__ float As[64][68];
  __shared__ float Ws[64][132];
  const int t  = threadIdx.x;
  const int row0 = blockIdx.x * 64;
  const int tx = t & 15;
  const int ty = t >> 4;

  float acc[4][8];
#pragma unroll
  for (int i = 0; i < 4; ++i)
#pragma unroll
    for (int j = 0; j < 8; ++j) acc[i][j] = 0.f;

  const int la_k = t & 15;
  const int la_r = t >> 4;
  const int lw_c = t & 31;
  const int lw_k = t >> 5;

  for (int k0 = 0; k0 < K; k0 += 64) {
    __syncthreads();
#pragma unroll
    for (int p = 0; p < 4; ++p) {
      int r = row0 + la_r + 16 * p;
      r = r < M ? r : M - 1;
      const float4 v = *(const float4*)&A[(size_t)r * K + k0 + la_k * 4];
      As[la_k * 4 + 0][la_r + 16 * p] = v.x;
      As[la_k * 4 + 1][la_r + 16 * p] = v.y;
      As[la_k * 4 + 2][la_r + 16 * p] = v.z;
      As[la_k * 4 + 3][la_r + 16 * p] = v.w;
    }
#pragma unroll
    for (int q = 0; q < 8; ++q) {
      const int kk = lw_k + 8 * q;
      *(float4*)&Ws[kk][lw_c * 4] =
          *(const float4*)&W[(size_t)(k0 + kk) * HID + lw_c * 4];
    }
    __syncthreads();
#pragma unroll 4
    for (int kk = 0; kk < 64; ++kk) {
      const float4 a  = *(const float4*)&As[kk][ty * 4];
      const float4 w0 = *(const float4*)&Ws[kk][tx * 4];
      const float4 w1 = *(const float4*)&Ws[kk][64 + tx * 4];
      const float av[4] = {a.x, a.y, a.z, a.w};
      const float wv[8] = {w0.x, w0.y, w0.z, w0.w, w1.x, w1.y, w1.z, w1.w};
#pragma unroll
      for (int i = 0; i < 4; ++i)
#pragma unroll
        for (int j = 0; j < 8; ++j) acc[i][j] += av[i] * wv[j];
    }
  }

  const float4 b0 = *(const float4*)&bias[tx * 4];
  const float4 b1 = *(const float4*)&bias[64 + tx * 4];
#pragma unroll
  for (int i = 0; i < 4; ++i) {
    const int r = row0 + ty * 4 + i;
    if (r < M) {
      float4 o0 = {acc[i][0] + b0.x, acc[i][1] + b0.y,
                   acc[i][2] + b0.z, acc[i][3] + b0.w};
      float4 o1 = {acc[i][4] + b1.x, acc[i][5] + b1.y,
                   acc[i][6] + b1.z, acc[i][7] + b1.w};
      *(float4*)&C[(size_t)r * HID + tx * 4] = o0;
      *(float4*)&C[(size_t)r * HID + 64 + tx * 4] = o1;
    }
  }
}

// ---------------------------------------------------------------------------
// in-degree counts
// ---------------------------------------------------------------------------
__global__ __launch_bounds__(256)
void count_deg(const int* __restrict__ dst, int* __restrict__ cnt, int n) {
  const int i = blockIdx.x * 256 + threadIdx.x;
  if (i < n) atomicAdd(&cnt[dst[i]], 1);
}

// ---------------------------------------------------------------------------
// single-block exclusive scan of cnt[0..n) into pos[0..n) (CSR row starts).
// 1024 threads, each owns a contiguous chunk; Hillis-Steele on partials.
// ---------------------------------------------------------------------------
__global__ __launch_bounds__(1024)
void scan_offsets(const int* __restrict__ cnt, int n, int* __restrict__ pos) {
  __shared__ int part[1024];
  const int t = threadIdx.x;
  const int chunk = (n + 1023) / 1024;
  const int lo = t * chunk;
  const int hi = (lo + chunk < n) ? lo + chunk : n;
  int s = 0;
  for (int i = lo; i < hi; ++i) s += cnt[i];
  part[t] = s;
  __syncthreads();
  for (int d = 1; d < 1024; d <<= 1) {
    int v = 0;
    if (t >= d) v = part[t - d];
    __syncthreads();
    if (t >= d) part[t] += v;
    __syncthreads();
  }
  int run = (t == 0) ? 0 : part[t - 1];
  for (int i = lo; i < hi; ++i) {
    pos[i] = run;
    run += cnt[i];
  }
}

// ---------------------------------------------------------------------------
// CSR fill: elist[pos[dst[e]]++] = src[e].  After this, pos[d] == row_end(d);
// row_beg(d) = pos[d] - cnt[d].
// ---------------------------------------------------------------------------
__global__ __launch_bounds__(256)
void fill_elist(const int* __restrict__ src, const int* __restrict__ dst,
                int* __restrict__ pos, int* __restrict__ elist, int n) {
  const int e = blockIdx.x * 256 + threadIdx.x;
  if (e < n) {
    const int p = atomicAdd(&pos[dst[e]], 1);
    elist[p] = src[e];
  }
}

// ---------------------------------------------------------------------------
// gather segment-mean: out[d] = mean over elist rows of wh, + optional leaky.
// 32 lanes per destination row (float4 each), 8 rows per block.
// ---------------------------------------------------------------------------
template<bool DO_LEAKY>
__global__ __launch_bounds__(256)
void gather_mean(const float* __restrict__ wh, const int* __restrict__ pos,
                 const int* __restrict__ cnt, const int* __restrict__ elist,
                 float* __restrict__ out, int nrows) {
  const int row = blockIdx.x * 8 + (threadIdx.x >> 5);
  if (row >= nrows) return;
  const int c = threadIdx.x & 31;
  const int end = pos[row];
  const int cn  = cnt[row];
  const int beg = end - cn;
  float4 acc = {0.f, 0.f, 0.f, 0.f};
  for (int i = beg; i < end; ++i) {
    const int s = elist[i];
    const float4 v = ((const float4*)wh)[(size_t)s * 32 + c];
    acc.x += v.x; acc.y += v.y; acc.z += v.z; acc.w += v.w;
  }
  const float inv = cn > 0 ? 1.0f / (float)cn : 0.0f;
  acc.x *= inv; acc.y *= inv; acc.z *= inv; acc.w *= inv;
  if (DO_LEAKY) {
    acc.x = acc.x > 0.f ? acc.x : LEAKY_SLOPE * acc.x;
    acc.y = acc.y > 0.f ? acc.y : LEAKY_SLOPE * acc.y;
    acc.z = acc.z > 0.f ? acc.z : LEAKY_SLOPE * acc.z;
    acc.w = acc.w > 0.f ? acc.w : LEAKY_SLOPE * acc.w;
  }
  ((float4*)out)[(size_t)row * 32 + c] = acc;
}

// ---------------------------------------------------------------------------
// out[M,16] = H[M,128] @ W[128,16] + bias
// ---------------------------------------------------------------------------
__global__ __launch_bounds__(256)
void gemm_out16(const float* __restrict__ H, const float* __restrict__ W,
                const float* __restrict__ bias, float* __restrict__ out, int M) {
  __shared__ float Ws[HID * OUT_DIM];
  __shared__ float Hs[16 * HID];
  const int t = threadIdx.x;
  const int row0 = blockIdx.x * 16;
  {
    const float4* s0 = (const float4*)W;
    float4* dp = (float4*)Ws;
    dp[t]       = s0[t];
    dp[t + 256] = s0[t + 256];
    const float4* s1 = (const float4*)(H + (size_t)row0 * HID);
    float4* hp = (float4*)Hs;
    hp[t]       = s1[t];
    hp[t + 256] = s1[t + 256];
  }
  __syncthreads();
  const int r = t >> 4, c = t & 15;
  float s = bias[c];
  const float* h = &Hs[r * HID];
#pragma unroll 8
  for (int k = 0; k < HID; ++k) s += h[k] * Ws[k * OUT_DIM + c];
  out[(size_t)(row0 + r) * OUT_DIM + c] = s;
}

// ---------------------------------------------------------------------------
extern "C" void kernel_launch(void* const* d_in, const int* in_sizes, int n_in,
                              void* d_out, int out_size, void* d_ws, size_t ws_size,
                              hipStream_t stream) {
  const float* feat_user  = (const float*)d_in[0];
  // d_in[1] feat_item : dead (never reaches the output)
  const int*   src_clicks = (const int*)d_in[2];
  const int*   dst_clicks = (const int*)d_in[3];
  const int*   src_cb     = (const int*)d_in[4];
  const int*   dst_cb     = (const int*)d_in[5];
  const float* Win_user   = (const float*)d_in[6];
  const float* bin_user   = (const float*)d_in[7];
  // d_in[8..9] Win_item/bin_item : dead
  const float* W0_clicks  = (const float*)d_in[10];
  const float* b0_clicks  = (const float*)d_in[11];
  // d_in[12..15] W0_cb/b0_cb/W1_clicks/b1_clicks : dead
  const float* W1_cb      = (const float*)d_in[16];
  const float* b1_cb      = (const float*)d_in[17];
  const float* Wout       = (const float*)d_in[18];
  const float* bout       = (const float*)d_in[19];
  float* out = (float*)d_out;

  const size_t SZ = (size_t)N_USER * HID * sizeof(float);  // 51.2 MB each
  char* ws = (char*)d_ws;
  float* buf0 = (float*)ws;                       // x_u -> h_i0 -> h_u1
  float* buf1 = (float*)(ws + SZ);                // wh_u0 -> wh_i1
  int* cnt_item  = (int*)(ws + 2 * SZ);           // deg of dst_clicks
  int* cnt_user  = cnt_item + N_ITEM;             // deg of dst_cb
  int* pos_clk   = cnt_user + N_USER;             // CSR cursor/row-end (clicks)
  int* pos_cb    = pos_clk + N_ITEM;              // CSR cursor/row-end (cb)
  int* elist_clk = pos_cb + N_USER;               // 1M src ids sorted by dst
  int* elist_cb  = elist_clk + N_EDGE;

  const int G64 = (N_USER + 63) / 64;             // 1563
  const int GG  = (N_USER + 7) / 8;               // 12500 (gather: 8 rows/block)

  // --- CSR build for both relations ---
  hipMemsetAsync(cnt_item, 0, (size_t)(N_ITEM + N_USER) * sizeof(int), stream);
  count_deg<<<(N_EDGE + 255) / 256, 256, 0, stream>>>(dst_clicks, cnt_item, N_EDGE);
  count_deg<<<(N_EDGE + 255) / 256, 256, 0, stream>>>(dst_cb, cnt_user, N_EDGE);
  scan_offsets<<<1, 1024, 0, stream>>>(cnt_item, N_ITEM, pos_clk);
  scan_offsets<<<1, 1024, 0, stream>>>(cnt_user, N_USER, pos_cb);
  fill_elist<<<(N_EDGE + 255) / 256, 256, 0, stream>>>(src_clicks, dst_clicks, pos_clk, elist_clk, N_EDGE);
  fill_elist<<<(N_EDGE + 255) / 256, 256, 0, stream>>>(src_cb, dst_cb, pos_cb, elist_cb, N_EDGE);

  // 1) x_u = feat_user @ Win_user + bin_user        -> buf0
  gemm_bias_128<IN_DIM><<<G64, 256, 0, stream>>>(feat_user, Win_user, bin_user, buf0, N_USER);
  // 2) wh_u0 = x_u @ W0_clicks + b0_clicks          -> buf1
  gemm_bias_128<HID><<<G64, 256, 0, stream>>>(buf0, W0_clicks, b0_clicks, buf1, N_USER);
  // 3) h_i0 = leaky(seg_mean(wh_u0[src], dst))      -> buf0
  gather_mean<true><<<GG, 256, 0, stream>>>(buf1, pos_clk, cnt_item, elist_clk, buf0, N_ITEM);
  // 4) wh_i1 = h_i0 @ W1_cb + b1_cb                 -> buf1
  gemm_bias_128<HID><<<G64, 256, 0, stream>>>(buf0, W1_cb, b1_cb, buf1, N_ITEM);
  // 5) h_u1 = seg_mean(wh_i1[src], dst)             -> buf0
  gather_mean<false><<<GG, 256, 0, stream>>>(buf1, pos_cb, cnt_user, elist_cb, buf0, N_USER);
  // 6) out = h_u1 @ Wout + bout
  gemm_out16<<<N_USER / 16, 256, 0, stream>>>(buf0, Wout, bout, out, N_USER);
}

// Round 3
// 804.245 us; speedup vs baseline: 4.8586x; 1.3721x over previous
//
#include <hip/hip_runtime.h>
#include <cstddef>
#include <cstdint>

#define N_USER 100000
#define N_ITEM 100000
#define N_EDGE 1000000
#define IN_DIM 256
#define HID 128
#define OUT_DIM 16
#define LEAKY_SLOPE 0.01f
#define SCAN_BLK 391   // ceil(100000/256)

// ---------------------------------------------------------------------------
// C[M,128] = A[M,K] @ W[K,128] + bias   (K multiple of 64; fp32 vector ALU)
// ---------------------------------------------------------------------------
template<int K>
__global__ __launch_bounds__(256)
void gemm_bias_128(const float* __restrict__ A, const float* __restrict__ W,
                   const float* __restrict__ bias, float* __restrict__ C, int M) {
  __shared__ float As[64][68];
  __shared__ float Ws[64][132];
  const int t  = threadIdx.x;
  const int row0 = blockIdx.x * 64;
  const int tx = t & 15;
  const int ty = t >> 4;

  float acc[4][8];
#pragma unroll
  for (int i = 0; i < 4; ++i)
#pragma unroll
    for (int j = 0; j < 8; ++j) acc[i][j] = 0.f;

  const int la_k = t & 15;
  const int la_r = t >> 4;
  const int lw_c = t & 31;
  const int lw_k = t >> 5;

  for (int k0 = 0; k0 < K; k0 += 64) {
    __syncthreads();
#pragma unroll
    for (int p = 0; p < 4; ++p) {
      int r = row0 + la_r + 16 * p;
      r = r < M ? r : M - 1;
      const float4 v = *(const float4*)&A[(size_t)r * K + k0 + la_k * 4];
      As[la_k * 4 + 0][la_r + 16 * p] = v.x;
      As[la_k * 4 + 1][la_r + 16 * p] = v.y;
      As[la_k * 4 + 2][la_r + 16 * p] = v.z;
      As[la_k * 4 + 3][la_r + 16 * p] = v.w;
    }
#pragma unroll
    for (int q = 0; q < 8; ++q) {
      const int kk = lw_k + 8 * q;
      *(float4*)&Ws[kk][lw_c * 4] =
          *(const float4*)&W[(size_t)(k0 + kk) * HID + lw_c * 4];
    }
    __syncthreads();
#pragma unroll 4
    for (int kk = 0; kk < 64; ++kk) {
      const float4 a  = *(const float4*)&As[kk][ty * 4];
      const float4 w0 = *(const float4*)&Ws[kk][tx * 4];
      const float4 w1 = *(const float4*)&Ws[kk][64 + tx * 4];
      const float av[4] = {a.x, a.y, a.z, a.w};
      const float wv[8] = {w0.x, w0.y, w0.z, w0.w, w1.x, w1.y, w1.z, w1.w};
#pragma unroll
      for (int i = 0; i < 4; ++i)
#pragma unroll
        for (int j = 0; j < 8; ++j) acc[i][j] += av[i] * wv[j];
    }
  }

  const float4 b0 = *(const float4*)&bias[tx * 4];
  const float4 b1 = *(const float4*)&bias[64 + tx * 4];
#pragma unroll
  for (int i = 0; i < 4; ++i) {
    const int r = row0 + ty * 4 + i;
    if (r < M) {
      float4 o0 = {acc[i][0] + b0.x, acc[i][1] + b0.y,
                   acc[i][2] + b0.z, acc[i][3] + b0.w};
      float4 o1 = {acc[i][4] + b1.x, acc[i][5] + b1.y,
                   acc[i][6] + b1.z, acc[i][7] + b1.w};
      *(float4*)&C[(size_t)r * HID + tx * 4] = o0;
      *(float4*)&C[(size_t)r * HID + 64 + tx * 4] = o1;
    }
  }
}

// ---------------------------------------------------------------------------
// degree counts, both relations batched over blockIdx.y
// ---------------------------------------------------------------------------
__global__ __launch_bounds__(256)
void count_deg2(const int* __restrict__ dstA, const int* __restrict__ dstB,
                int* __restrict__ cntA, int* __restrict__ cntB, int n) {
  const int i = blockIdx.x * 256 + threadIdx.x;
  const int* __restrict__ dst = blockIdx.y ? dstB : dstA;
  int* __restrict__ cnt = blockIdx.y ? cntB : cntA;
  if (i < n) atomicAdd(&cnt[dst[i]], 1);
}

// ---------------------------------------------------------------------------
// 3-phase multi-block exclusive scan, batched over blockIdx.y (2 relations).
// cnt/pos are per-relation contiguous (stride n); bsum stride SCAN_BLK.
// ---------------------------------------------------------------------------
__global__ __launch_bounds__(256)
void scan_p1(const int* __restrict__ cntBase, int n, int* __restrict__ posBase,
             int* __restrict__ bsumBase) {
  __shared__ int sh[256];
  const int y = blockIdx.y, b = blockIdx.x, t = threadIdx.x;
  const int* cnt = cntBase + (size_t)y * n;
  int* pos = posBase + (size_t)y * n;
  int* bsum = bsumBase + (size_t)y * SCAN_BLK;
  const int i = b * 256 + t;
  const int v = (i < n) ? cnt[i] : 0;
  sh[t] = v;
  __syncthreads();
#pragma unroll
  for (int d = 1; d < 256; d <<= 1) {
    const int x = (t >= d) ? sh[t - d] : 0;
    __syncthreads();
    sh[t] += x;
    __syncthreads();
  }
  if (i < n) pos[i] = sh[t] - v;          // exclusive within block
  if (t == 255) bsum[b] = sh[255];        // block total
}

__global__ __launch_bounds__(512)
void scan_p2(int* __restrict__ bsumBase, int nblk) {
  __shared__ int sh[512];
  int* bsum = bsumBase + (size_t)blockIdx.x * SCAN_BLK;
  const int t = threadIdx.x;
  const int v = (t < nblk) ? bsum[t] : 0;
  sh[t] = v;
  __syncthreads();
#pragma unroll
  for (int d = 1; d < 512; d <<= 1) {
    const int x = (t >= d) ? sh[t - d] : 0;
    __syncthreads();
    sh[t] += x;
    __syncthreads();
  }
  if (t < nblk) bsum[t] = sh[t] - v;      // exclusive across blocks
}

__global__ __launch_bounds__(256)
void scan_p3(int* __restrict__ posBase, const int* __restrict__ bsumBase, int n) {
  const int y = blockIdx.y;
  int* pos = posBase + (size_t)y * n;
  const int* bsum = bsumBase + (size_t)y * SCAN_BLK;
  const int i = blockIdx.x * 256 + threadIdx.x;
  if (i < n) pos[i] += bsum[blockIdx.x];
}

// ---------------------------------------------------------------------------
// CSR fill (batched): elist[pos[dst[e]]++] = src[e]. Afterwards pos[d] is
// row end; row begin = pos[d] - cnt[d].
// ---------------------------------------------------------------------------
__global__ __launch_bounds__(256)
void fill_elist2(const int* __restrict__ srcA, const int* __restrict__ dstA,
                 int* __restrict__ posA, int* __restrict__ elistA,
                 const int* __restrict__ srcB, const int* __restrict__ dstB,
                 int* __restrict__ posB, int* __restrict__ elistB, int n) {
  const int e = blockIdx.x * 256 + threadIdx.x;
  if (e >= n) return;
  const int* src; const int* dst; int* pos; int* elist;
  if (blockIdx.y) { src = srcB; dst = dstB; pos = posB; elist = elistB; }
  else            { src = srcA; dst = dstA; pos = posA; elist = elistA; }
  const int p = atomicAdd(&pos[dst[e]], 1);
  elist[p] = src[e];
}

// ---------------------------------------------------------------------------
// gather segment-mean: out[d] = mean over elist rows of wh, + optional leaky.
// 32 lanes per destination row (float4 each), 8 rows per block.
// ---------------------------------------------------------------------------
template<bool DO_LEAKY>
__global__ __launch_bounds__(256)
void gather_mean(const float* __restrict__ wh, const int* __restrict__ pos,
                 const int* __restrict__ cnt, const int* __restrict__ elist,
                 float* __restrict__ out, int nrows) {
  const int row = blockIdx.x * 8 + (threadIdx.x >> 5);
  if (row >= nrows) return;
  const int c = threadIdx.x & 31;
  const int end = pos[row];
  const int cn  = cnt[row];
  const int beg = end - cn;
  float4 acc = {0.f, 0.f, 0.f, 0.f};
  for (int i = beg; i < end; ++i) {
    const int s = elist[i];
    const float4 v = ((const float4*)wh)[(size_t)s * 32 + c];
    acc.x += v.x; acc.y += v.y; acc.z += v.z; acc.w += v.w;
  }
  const float inv = cn > 0 ? 1.0f / (float)cn : 0.0f;
  acc.x *= inv; acc.y *= inv; acc.z *= inv; acc.w *= inv;
  if (DO_LEAKY) {
    acc.x = acc.x > 0.f ? acc.x : LEAKY_SLOPE * acc.x;
    acc.y = acc.y > 0.f ? acc.y : LEAKY_SLOPE * acc.y;
    acc.z = acc.z > 0.f ? acc.z : LEAKY_SLOPE * acc.z;
    acc.w = acc.w > 0.f ? acc.w : LEAKY_SLOPE * acc.w;
  }
  ((float4*)out)[(size_t)row * 32 + c] = acc;
}

// ---------------------------------------------------------------------------
// out[M,16] = H[M,128] @ W[128,16] + bias
// ---------------------------------------------------------------------------
__global__ __launch_bounds__(256)
void gemm_out16(const float* __restrict__ H, const float* __restrict__ W,
                const float* __restrict__ bias, float* __restrict__ out, int M) {
  __shared__ float Ws[HID * OUT_DIM];
  __shared__ float Hs[16 * HID];
  const int t = threadIdx.x;
  const int row0 = blockIdx.x * 16;
  {
    const float4* s0 = (const float4*)W;
    float4* dp = (float4*)Ws;
    dp[t]       = s0[t];
    dp[t + 256] = s0[t + 256];
    const float4* s1 = (const float4*)(H + (size_t)row0 * HID);
    float4* hp = (float4*)Hs;
    hp[t]       = s1[t];
    hp[t + 256] = s1[t + 256];
  }
  __syncthreads();
  const int r = t >> 4, c = t & 15;
  float s = bias[c];
  const float* h = &Hs[r * HID];
#pragma unroll 8
  for (int k = 0; k < HID; ++k) s += h[k] * Ws[k * OUT_DIM + c];
  out[(size_t)(row0 + r) * OUT_DIM + c] = s;
}

// ---------------------------------------------------------------------------
extern "C" void kernel_launch(void* const* d_in, const int* in_sizes, int n_in,
                              void* d_out, int out_size, void* d_ws, size_t ws_size,
                              hipStream_t stream) {
  const float* feat_user  = (const float*)d_in[0];
  // d_in[1] feat_item : dead (never reaches the output)
  const int*   src_clicks = (const int*)d_in[2];
  const int*   dst_clicks = (const int*)d_in[3];
  const int*   src_cb     = (const int*)d_in[4];
  const int*   dst_cb     = (const int*)d_in[5];
  const float* Win_user   = (const float*)d_in[6];
  const float* bin_user   = (const float*)d_in[7];
  // d_in[8..9] Win_item/bin_item : dead
  const float* W0_clicks  = (const float*)d_in[10];
  const float* b0_clicks  = (const float*)d_in[11];
  // d_in[12..15] W0_cb/b0_cb/W1_clicks/b1_clicks : dead
  const float* W1_cb      = (const float*)d_in[16];
  const float* b1_cb      = (const float*)d_in[17];
  const float* Wout       = (const float*)d_in[18];
  const float* bout       = (const float*)d_in[19];
  float* out = (float*)d_out;

  const size_t SZ = (size_t)N_USER * HID * sizeof(float);  // 51.2 MB each
  char* ws = (char*)d_ws;
  float* buf0 = (float*)ws;                       // x_u -> h_i0 -> h_u1
  float* buf1 = (float*)(ws + SZ);                // wh_u0 -> wh_i1
  int* cnt_item  = (int*)(ws + 2 * SZ);           // deg of dst_clicks
  int* cnt_user  = cnt_item + N_ITEM;             // deg of dst_cb  (contiguous!)
  int* pos_clk   = cnt_user + N_USER;             // CSR cursor/row-end (clicks)
  int* pos_cb    = pos_clk + N_ITEM;              // (contiguous!)
  int* elist_clk = pos_cb + N_USER;               // 1M src ids sorted by dst
  int* elist_cb  = elist_clk + N_EDGE;
  int* bsum      = elist_cb + N_EDGE;             // 2 * SCAN_BLK block sums

  const int G64 = (N_USER + 63) / 64;             // 1563
  const int GG  = (N_USER + 7) / 8;               // 12500
  const int GE  = (N_EDGE + 255) / 256;           // 3907

  // --- CSR build for both relations (batched over blockIdx.y) ---
  hipMemsetAsync(cnt_item, 0, (size_t)(N_ITEM + N_USER) * sizeof(int), stream);
  count_deg2<<<dim3(GE, 2), 256, 0, stream>>>(dst_clicks, dst_cb, cnt_item, cnt_user, N_EDGE);
  scan_p1<<<dim3(SCAN_BLK, 2), 256, 0, stream>>>(cnt_item, N_ITEM, pos_clk, bsum);
  scan_p2<<<2, 512, 0, stream>>>(bsum, SCAN_BLK);
  scan_p3<<<dim3(SCAN_BLK, 2), 256, 0, stream>>>(pos_clk, bsum, N_ITEM);
  fill_elist2<<<dim3(GE, 2), 256, 0, stream>>>(src_clicks, dst_clicks, pos_clk, elist_clk,
                                               src_cb, dst_cb, pos_cb, elist_cb, N_EDGE);

  // 1) x_u = feat_user @ Win_user + bin_user        -> buf0
  gemm_bias_128<IN_DIM><<<G64, 256, 0, stream>>>(feat_user, Win_user, bin_user, buf0, N_USER);
  // 2) wh_u0 = x_u @ W0_clicks + b0_clicks          -> buf1
  gemm_bias_128<HID><<<G64, 256, 0, stream>>>(buf0, W0_clicks, b0_clicks, buf1, N_USER);
  // 3) h_i0 = leaky(seg_mean(wh_u0[src], dst))      -> buf0
  gather_mean<true><<<GG, 256, 0, stream>>>(buf1, pos_clk, cnt_item, elist_clk, buf0, N_ITEM);
  // 4) wh_i1 = h_i0 @ W1_cb + b1_cb                 -> buf1
  gemm_bias_128<HID><<<G64, 256, 0, stream>>>(buf0, W1_cb, b1_cb, buf1, N_ITEM);
  // 5) h_u1 = seg_mean(wh_i1[src], dst)             -> buf0
  gather_mean<false><<<GG, 256, 0, stream>>>(buf1, pos_cb, cnt_user, elist_cb, buf0, N_USER);
  // 6) out = h_u1 @ Wout + bout
  gemm_out16<<<N_USER / 16, 256, 0, stream>>>(buf0, Wout, bout, out, N_USER);
}